// Round 13
// baseline (360.034 us; speedup 1.0000x reference)
//
#include <hip/hip_runtime.h>
#include <math.h>

#define N_ 8192
#define D_ 512
#define NC_ 128
#define T_ 64      // 8192/128 row-tiles
#define BK_ 32     // K-step
#define KSTEPS 16  // 512/32
#define NBLK 2080  // T_*(T_+1)/2

typedef __attribute__((ext_vector_type(8))) short bf16x8;
typedef __attribute__((ext_vector_type(4))) float f32x4;
typedef __attribute__((ext_vector_type(4))) unsigned short us4;

static __device__ __forceinline__ unsigned short f2bf(float f) {
    union { float f; unsigned u; } c; c.f = f;
    unsigned u = c.u;
    u += 0x7fffu + ((u >> 16) & 1u);   // round-to-nearest-even
    return (unsigned short)(u >> 16);
}

// ---------- kernel 1: convert + last-row fp64 dots + histogram (wide) --------
__global__ __launch_bounds__(256) void k_pre(const float* __restrict__ x,
                                             unsigned short* __restrict__ xb,
                                             const int* __restrict__ tg,
                                             double* __restrict__ sim_last,
                                             int* __restrict__ hist32,
                                             double* __restrict__ gd,
                                             int* __restrict__ gi) {
    const int bid = blockIdx.x;
    const int tid = threadIdx.x;
    if (bid == 0 && tid == 0) {
        atomicExch((unsigned long long*)&gd[0], 0ull);
        atomicExch((unsigned long long*)&gd[1], 0ull);
        atomicExch((unsigned long long*)&gd[2], 0ull);
        atomicExch(&gi[0], 0); atomicExch(&gi[1], 0);
        atomicExch(&gi[2], 0); atomicExch(&gi[3], 0);
        atomicExch(&gi[5], 0);            // k_main completion counter
    }
    if (bid < 4096) {
        int i = bid * 256 + tid;
        float4 v = reinterpret_cast<const float4*>(x)[i];
        us4 o = { f2bf(v.x), f2bf(v.y), f2bf(v.z), f2bf(v.w) };
        reinterpret_cast<us4*>(xb)[i] = o;
    } else if (bid < 6144) {
        int j    = (bid - 4096) * 4 + (tid >> 6);
        int lane = tid & 63;
        const float* xl = x + (size_t)(N_ - 1) * D_;
        const float* xj = x + (size_t)j * D_;
        double acc = 0.0;
#pragma unroll
        for (int it = 0; it < 8; ++it) {
            int k = it * 64 + lane;
            acc += (double)xl[k] * (double)xj[k];
        }
#pragma unroll
        for (int m = 32; m >= 1; m >>= 1) acc += __shfl_xor(acc, m, 64);
        if (lane == 0) sim_last[j] = acc;
    } else {
        __shared__ int lh[NC_];
        int b = bid - 6144;                 // 0..31
        if (tid < NC_) lh[tid] = 0;
        __syncthreads();
        atomicAdd(&lh[tg[b * 256 + tid]], 1);
        __syncthreads();
        if (tid < NC_) hist32[b * NC_ + tid] = lh[tid];
    }
}

// ---------- kernel 2: R11 k_main verbatim + fused finisher (2 launches total) -
// GEMM part: grid 2080 triangular pairs, 128x128 tile, BK=32, 32 KiB LDS ->
// 4 blocks/CU, counted-vmcnt 2-deep pipeline (R11, best measured: 72.9 us).
// Finisher: each block bumps gi[5] after its stores (threadfence-released);
// the 64 blocks with tickets >= NBLK-64 spin until gi[5]==NBLK, acquire-fence,
// then run the R11 k_post body for tile t = ticket-(NBLK-64), with its shared
// arrays aliased into the dead As buffer (no extra LDS, occupancy preserved).
__global__ __launch_bounds__(256, 4) void k_main(const unsigned short* __restrict__ xb,
                                                 const int* __restrict__ tg,
                                                 float* __restrict__ bufP,
                                                 float* __restrict__ bufN,
                                                 const int* __restrict__ hist32,
                                                 const double* __restrict__ sim_last,
                                                 double* __restrict__ gd,
                                                 int* __restrict__ gi,
                                                 float* __restrict__ out) {
    __shared__ alignas(16) unsigned short As[2][128 * BK_];   // 16 KiB
    __shared__ alignas(16) unsigned short Bs[2][128 * BK_];   // 16 KiB
    __shared__ int sh_fin;

    const int tid  = threadIdx.x;
    const int w    = tid >> 6;
    const int lane = tid & 63;
    const int q    = lane >> 4;
    const int l15  = lane & 15;
    const int wrow = w >> 1;      // 0..1
    const int wcol = w & 1;       // 0..1

    // XCD-chunked bijective swizzle (2080 = 8*260)
    const int bswz = (blockIdx.x & 7) * 260 + (blockIdx.x >> 3);

    // triangular decode: bswz -> (it, jt), it<=jt
    int rem = bswz;
    int it = 0;
    while (rem >= (T_ - it)) { rem -= (T_ - it); it++; }
    const int jt = it + rem;
    const int row0 = it * 128;
    const int col0 = jt * 128;

    // stage A(128x32) + B(128x32) of K-tile kt into buffer p: 4 gload_lds/thread.
    // XOR-swizzled source: LDS slot sl (of 4/row) holds kgroup g = sl ^ ((r>>1)&3).
    auto stage_tile = [&](int p, int kt) {
        const int k0 = kt * BK_;
#pragma unroll
        for (int itr = 0; itr < 2; ++itr) {
            int slot = itr * 4 + w;          // 0..7
            int gs = slot * 64 + lane;       // 16B-chunk id 0..511
            int r  = gs >> 2;                // row 0..127
            int sl = gs & 3;
            int g  = sl ^ ((r >> 1) & 3);
            const unsigned short* ga = xb + (size_t)(row0 + r) * D_ + k0 + g * 8;
            const unsigned short* gb = xb + (size_t)(col0 + r) * D_ + k0 + g * 8;
            __builtin_amdgcn_global_load_lds(
                (const __attribute__((address_space(1))) void*)ga,
                (__attribute__((address_space(3))) void*)(&As[p][0] + slot * 512),
                16, 0, 0);
            __builtin_amdgcn_global_load_lds(
                (const __attribute__((address_space(1))) void*)gb,
                (__attribute__((address_space(3))) void*)(&Bs[p][0] + slot * 512),
                16, 0, 0);
        }
    };

    f32x4 acc[4][4];
#pragma unroll
    for (int mi = 0; mi < 4; ++mi)
#pragma unroll
        for (int ni = 0; ni < 4; ++ni)
            acc[mi][ni] = (f32x4){0.f, 0.f, 0.f, 0.f};

    // one K-tile: 8 ds_read_b128 -> 16 MFMA
    auto compute_tile = [&](int p) {
        bf16x8 aF[4], bF[4];
#pragma unroll
        for (int mi = 0; mi < 4; ++mi) {
            int rA = wrow * 64 + mi * 16 + l15;
            int sl = q ^ ((rA >> 1) & 3);
            aF[mi] = *reinterpret_cast<const bf16x8*>(&As[p][0] + rA * BK_ + sl * 8);
        }
#pragma unroll
        for (int ni = 0; ni < 4; ++ni) {
            int rB = wcol * 64 + ni * 16 + l15;
            int sl = q ^ ((rB >> 1) & 3);
            bF[ni] = *reinterpret_cast<const bf16x8*>(&Bs[p][0] + rB * BK_ + sl * 8);
        }
        asm volatile("s_waitcnt lgkmcnt(0)" ::: "memory");
        __builtin_amdgcn_sched_barrier(0);   // rule 18: MFMA must not hoist
        __builtin_amdgcn_s_setprio(1);
#pragma unroll
        for (int mi = 0; mi < 4; ++mi)
#pragma unroll
            for (int ni = 0; ni < 4; ++ni)
                acc[mi][ni] = __builtin_amdgcn_mfma_f32_16x16x32_bf16(
                    aF[mi], bF[ni], acc[mi][ni], 0, 0, 0);
        __builtin_amdgcn_s_setprio(0);
    };

#define TILE(P, KS, DOSTAGE, VMN)                                         \
    do {                                                                  \
        asm volatile("s_waitcnt vmcnt(" #VMN ")" ::: "memory");           \
        __builtin_amdgcn_s_barrier();                                     \
        __builtin_amdgcn_sched_barrier(0);                                \
        compute_tile(P);                                                  \
        __builtin_amdgcn_s_barrier();                                     \
        __builtin_amdgcn_sched_barrier(0);                                \
        if (DOSTAGE) stage_tile(P, (KS) + 2);                             \
    } while (0)

    // prologue: two K-tiles in flight (8 gload_lds/thread outstanding)
    stage_tile(0, 0);
    stage_tile(1, 1);

    TILE(0, 0, 1, 4);
    TILE(1, 1, 1, 4);
    TILE(0, 2, 1, 4);
    TILE(1, 3, 1, 4);
    TILE(0, 4, 1, 4);
    TILE(1, 5, 1, 4);
    TILE(0, 6, 1, 4);
    TILE(1, 7, 1, 4);
    TILE(0, 8, 1, 4);
    TILE(1, 9, 1, 4);
    TILE(0, 10, 1, 4);
    TILE(1, 11, 1, 4);
    TILE(0, 12, 1, 4);
    TILE(1, 13, 1, 4);
    TILE(0, 14, 0, 4);
    TILE(1, 15, 0, 0);
#undef TILE

    // ---------------- epilogue (R11 verbatim) ----------------
    int tC[4];
#pragma unroll
    for (int ni = 0; ni < 4; ++ni)
        tC[ni] = tg[col0 + wcol * 64 + ni * 16 + l15];

    float ps[4][4], ns[4][4];
    float cps[4], cns[4];
    int tR[4][4];
#pragma unroll
    for (int mi = 0; mi < 4; ++mi)
#pragma unroll
        for (int r = 0; r < 4; ++r) {
            ps[mi][r] = 0.f; ns[mi][r] = 0.f;
            tR[mi][r] = tg[row0 + wrow * 64 + mi * 16 + q * 4 + r];
        }
#pragma unroll
    for (int ni = 0; ni < 4; ++ni) { cps[ni] = 0.f; cns[ni] = 0.f; }

#pragma unroll
    for (int mi = 0; mi < 4; ++mi)
#pragma unroll
        for (int ni = 0; ni < 4; ++ni)
#pragma unroll
            for (int r = 0; r < 4; ++r) {
                float s = acc[mi][ni][r];
                bool same = (tR[mi][r] == tC[ni]);
                float e = __expf(same ? 1.0f - s : s);
                float pe = (same && (s < 1.0f)) ? e : 0.0f;
                float ne = same ? 0.0f : e;
                ps[mi][r] += pe; ns[mi][r] += ne;
                cps[ni]   += pe; cns[ni]   += ne;
            }

    // combine wave halves through LDS scratch = As[0] (buffer 1 held last tile)
    float* scr = (float*)As;         // [0:256)=rowP, [256:512)=rowN,
                                     // [512:768)=colP, [768:1024)=colN
#pragma unroll
    for (int mi = 0; mi < 4; ++mi)
#pragma unroll
        for (int r = 0; r < 4; ++r) {
            float p = ps[mi][r];
            float n = ns[mi][r];
#pragma unroll
            for (int m = 1; m < 16; m <<= 1) {
                p += __shfl_xor(p, m, 64);
                n += __shfl_xor(n, m, 64);
            }
            if (l15 == 0) {
                int rloc = wrow * 64 + mi * 16 + q * 4 + r;
                scr[wcol * 128 + rloc]       = p;
                scr[256 + wcol * 128 + rloc] = n;
            }
        }

#pragma unroll
    for (int ni = 0; ni < 4; ++ni) {
        float p = cps[ni];
        float n = cns[ni];
        p += __shfl_xor(p, 16, 64); p += __shfl_xor(p, 32, 64);
        n += __shfl_xor(n, 16, 64); n += __shfl_xor(n, 32, 64);
        if (q == 0) {
            int cloc = wcol * 64 + ni * 16 + l15;
            scr[512 + wrow * 128 + cloc] = p;
            scr[768 + wrow * 128 + cloc] = n;
        }
    }
    __syncthreads();

    if (tid < 128) {
        int r = tid;
        size_t off = ((size_t)it * T_ + jt) * 128 + r;
        bufP[off] = scr[r]       + scr[128 + r];
        bufN[off] = scr[256 + r] + scr[384 + r];
    } else if (jt != it) {
        int c = tid - 128;
        size_t off = ((size_t)jt * T_ + it) * 128 + c;
        bufP[off] = scr[512 + c] + scr[640 + c];
        bufN[off] = scr[768 + c] + scr[896 + c];
    }

    // ---------------- fused finisher (replaces k_post launch) ----------------
    __threadfence();                 // release this block's bufP/bufN stores
    __syncthreads();                 // all threads fenced before the ticket
    if (tid == 0) sh_fin = atomicAdd(&gi[5], 1);
    __syncthreads();
    const int fin = sh_fin - (NBLK - 64);
    if (fin < 0) return;

    if (tid == 0) {                  // spin until ALL blocks' stores released
        while (atomicAdd(&gi[5], 0) < NBLK) __builtin_amdgcn_s_sleep(8);
    }
    __syncthreads();
    __threadfence();                 // acquire: other blocks' stores visible

    // ---- R11 k_post body, t = fin; shared arrays aliased into dead As/Bs ----
    {
        const int t = fin;           // 0..63
        int*    lh = (int*)&As[0][0];                 // 512 B
        float*  sv = (float*)((char*)&As[0][0] + 512);        // 1 KiB
        double* Rd = (double*)((char*)&As[0][0] + 1536);      // 2 KiB
        double* Pd = Rd + 256;                                 // 2 KiB
        double* Nd = Pd + 256;                                 // 2 KiB
        int*    Ri = (int*)(Nd + 256);                         // 1 KiB
        int*    Pc = Ri + 256;                                 // 1 KiB
        int*    Nc = Pc + 256;                                 // 1 KiB (tot 10.5K)

        if (tid < NC_) {
            int a = 0;
#pragma unroll
            for (int b = 0; b < 32; ++b) a += hist32[b * NC_ + tid];
            lh[tid] = a;
        }

        const int half = tid >> 7;        // 0: psum, 1: nsum
        const int r    = tid & 127;
        const float* buf  = half ? bufN : bufP;
        const float* base = buf + (size_t)t * T_ * 128 + r;
        float s = 0.f;
#pragma unroll
        for (int o = 0; o < T_; ++o) s += base[o * 128];
        sv[tid] = s;
        __syncthreads();

        double rd = 0.0, pd = 0.0, nd = 0.0;
        int ri = 0, pc = 0, nc = 0;
        if (tid < 128) {
            int row = t * 128 + tid;
            bool ok = lh[tg[row]] < N_;
            rd = ok ? (double)(logf(sv[tid]) + logf(sv[128 + tid])) : 0.0;
            ri = ok ? 0 : 1;
            double sl = sim_last[row];
            int tlast = tg[N_ - 1];
            if (tg[row] == tlast) { if (sl < 1.0) { pd = sl; pc = 1; } }
            else                  { nd = sl; nc = 1; }
        }

        Rd[tid] = rd; Ri[tid] = ri;
        Pd[tid] = pd; Pc[tid] = pc;
        Nd[tid] = nd; Nc[tid] = nc;
        __syncthreads();
        for (int st = 128; st >= 1; st >>= 1) {
            if (tid < st) {
                Rd[tid] += Rd[tid + st]; Pd[tid] += Pd[tid + st]; Nd[tid] += Nd[tid + st];
                Ri[tid] += Ri[tid + st]; Pc[tid] += Pc[tid + st]; Nc[tid] += Nc[tid + st];
            }
            __syncthreads();
        }

        if (tid == 0) {
            atomicAdd(&gd[0], Rd[0]);
            atomicAdd(&gd[1], Pd[0]);
            atomicAdd(&gd[2], Nd[0]);
            atomicAdd(&gi[0], Ri[0]);
            atomicAdd(&gi[1], Pc[0]);
            atomicAdd(&gi[2], Nc[0]);
            __threadfence();
            int old = atomicAdd(&gi[3], 1);
            if (old == 63) {
                double A = atomicAdd(&gd[0], 0.0);
                double B = atomicAdd(&gd[1], 0.0);
                double C = atomicAdd(&gd[2], 0.0);
                int U = atomicAdd(&gi[0], 0);
                int V = atomicAdd(&gi[1], 0);
                int Y = atomicAdd(&gi[2], 0);
                out[0] = (float)(A / (double)N_);
                out[1] = (float)U / (float)N_;
                out[2] = (float)(B / (double)V);
                out[3] = (float)(C / (double)Y);
            }
        }
    }
}

extern "C" void kernel_launch(void* const* d_in, const int* in_sizes, int n_in,
                              void* d_out, int out_size, void* d_ws, size_t ws_size,
                              hipStream_t stream) {
    const float* x  = (const float*)d_in[0];
    const int*   tg = (const int*)d_in[1];
    char* ws = (char*)d_ws;

    unsigned short* xb = (unsigned short*)ws;                 // 8 MB
    const size_t XB = (size_t)N_ * D_ * 2;                    // 8388608
    float*  bufP = (float*)(ws + XB);                         // 2 MB
    float*  bufN = (float*)(ws + XB + 2097152);               // 2 MB
    double* sim_last = (double*)(ws + XB + 4194304);          // 64 KB
    int*    hist32   = (int*)(ws + XB + 4194304 + 65536);     // 16 KB
    double* gd   = (double*)(ws + XB + 4194304 + 65536 + 16384);      // 3 doubles
    int*    gi   = (int*)(ws + XB + 4194304 + 65536 + 16384 + 64);    // 16 ints

    hipLaunchKernelGGL(k_pre, dim3(4096 + 2048 + 32), dim3(256), 0, stream,
                       x, xb, tg, sim_last, hist32, gd, gi);
    hipLaunchKernelGGL(k_main, dim3(NBLK), dim3(256), 0, stream,
                       xb, tg, bufP, bufN, hist32, sim_last, gd, gi, (float*)d_out);
}

// Round 15
// 147.619 us; speedup vs baseline: 2.4389x; 2.4389x over previous
//
#include <hip/hip_runtime.h>
#include <math.h>

#define N_ 8192
#define D_ 512
#define NC_ 128
#define T_ 64      // 8192/128 row-tiles
#define BK_ 32     // K-step
#define KSTEPS 16  // 512/32

typedef __attribute__((ext_vector_type(8))) short bf16x8;
typedef __attribute__((ext_vector_type(4))) float f32x4;
typedef __attribute__((ext_vector_type(4))) unsigned short us4;

static __device__ __forceinline__ unsigned short f2bf(float f) {
    union { float f; unsigned u; } c; c.f = f;
    unsigned u = c.u;
    u += 0x7fffu + ((u >> 16) & 1u);   // round-to-nearest-even
    return (unsigned short)(u >> 16);
}

// ---------- kernel 1: convert + last-row fp64 dots + histogram (wide) --------
__global__ __launch_bounds__(256) void k_pre(const float* __restrict__ x,
                                             unsigned short* __restrict__ xb,
                                             const int* __restrict__ tg,
                                             double* __restrict__ sim_last,
                                             int* __restrict__ hist32,
                                             double* __restrict__ gd,
                                             int* __restrict__ gi) {
    const int bid = blockIdx.x;
    const int tid = threadIdx.x;
    if (bid == 0 && tid == 0) {
        atomicExch((unsigned long long*)&gd[0], 0ull);
        atomicExch((unsigned long long*)&gd[1], 0ull);
        atomicExch((unsigned long long*)&gd[2], 0ull);
        atomicExch(&gi[0], 0); atomicExch(&gi[1], 0);
        atomicExch(&gi[2], 0); atomicExch(&gi[3], 0);
    }
    if (bid < 4096) {
        int i = bid * 256 + tid;
        float4 v = reinterpret_cast<const float4*>(x)[i];
        us4 o = { f2bf(v.x), f2bf(v.y), f2bf(v.z), f2bf(v.w) };
        reinterpret_cast<us4*>(xb)[i] = o;
    } else if (bid < 6144) {
        int j    = (bid - 4096) * 4 + (tid >> 6);
        int lane = tid & 63;
        const float* xl = x + (size_t)(N_ - 1) * D_;
        const float* xj = x + (size_t)j * D_;
        double acc = 0.0;
#pragma unroll
        for (int it = 0; it < 8; ++it) {
            int k = it * 64 + lane;
            acc += (double)xl[k] * (double)xj[k];
        }
#pragma unroll
        for (int m = 32; m >= 1; m >>= 1) acc += __shfl_xor(acc, m, 64);
        if (lane == 0) sim_last[j] = acc;
    } else {
        __shared__ int lh[NC_];
        int b = bid - 6144;                 // 0..31
        if (tid < NC_) lh[tid] = 0;
        __syncthreads();
        atomicAdd(&lh[tg[b * 256 + tid]], 1);
        __syncthreads();
        if (tid < NC_) hist32[b * NC_ + tid] = lh[tid];
    }
}

// ---------- kernel 2: symmetric fused bf16 MFMA sim + masked exp partials ----
// R11 verbatim (best measured: k_main 72.9 us, total 146.5 us).
// grid = 2080 triangular tile-pairs (it<=jt), 128x128 tile, 256 threads.
// counted-vmcnt 2-deep pipeline at BK=32 / 32 KiB LDS -> 4 blocks/CU:
// per-tile barrier dead time of one block overlaps other blocks' MFMA while
// loads never drain mid-loop (steady s_waitcnt vmcnt(4) = waits only loads
// issued two tiles ago; vmcnt hits 0 once, at the last tile).
__global__ __launch_bounds__(256, 4) void k_main(const unsigned short* __restrict__ xb,
                                                 const int* __restrict__ tg,
                                                 float* __restrict__ bufP,
                                                 float* __restrict__ bufN) {
    __shared__ alignas(16) unsigned short As[2][128 * BK_];   // 16 KiB
    __shared__ alignas(16) unsigned short Bs[2][128 * BK_];   // 16 KiB

    const int tid  = threadIdx.x;
    const int w    = tid >> 6;
    const int lane = tid & 63;
    const int q    = lane >> 4;
    const int l15  = lane & 15;
    const int wrow = w >> 1;      // 0..1
    const int wcol = w & 1;       // 0..1

    // XCD-chunked bijective swizzle (2080 = 8*260)
    const int bswz = (blockIdx.x & 7) * 260 + (blockIdx.x >> 3);

    // triangular decode: bswz -> (it, jt), it<=jt
    int rem = bswz;
    int it = 0;
    while (rem >= (T_ - it)) { rem -= (T_ - it); it++; }
    const int jt = it + rem;
    const int row0 = it * 128;
    const int col0 = jt * 128;

    // stage A(128x32) + B(128x32) of K-tile kt into buffer p: 4 gload_lds/thread.
    // XOR-swizzled source: LDS slot sl (of 4/row) holds kgroup g = sl ^ ((r>>1)&3)
    // -> 2 lanes/bank on ds_read_b128 (free, m136).
    auto stage_tile = [&](int p, int kt) {
        const int k0 = kt * BK_;
#pragma unroll
        for (int itr = 0; itr < 2; ++itr) {
            int slot = itr * 4 + w;          // 0..7
            int gs = slot * 64 + lane;       // 16B-chunk id 0..511
            int r  = gs >> 2;                // row 0..127
            int sl = gs & 3;
            int g  = sl ^ ((r >> 1) & 3);
            const unsigned short* ga = xb + (size_t)(row0 + r) * D_ + k0 + g * 8;
            const unsigned short* gb = xb + (size_t)(col0 + r) * D_ + k0 + g * 8;
            __builtin_amdgcn_global_load_lds(
                (const __attribute__((address_space(1))) void*)ga,
                (__attribute__((address_space(3))) void*)(&As[p][0] + slot * 512),
                16, 0, 0);
            __builtin_amdgcn_global_load_lds(
                (const __attribute__((address_space(1))) void*)gb,
                (__attribute__((address_space(3))) void*)(&Bs[p][0] + slot * 512),
                16, 0, 0);
        }
    };

    f32x4 acc[4][4];
#pragma unroll
    for (int mi = 0; mi < 4; ++mi)
#pragma unroll
        for (int ni = 0; ni < 4; ++ni)
            acc[mi][ni] = (f32x4){0.f, 0.f, 0.f, 0.f};

    // one K-tile: 8 ds_read_b128 -> 16 MFMA
    auto compute_tile = [&](int p) {
        bf16x8 aF[4], bF[4];
#pragma unroll
        for (int mi = 0; mi < 4; ++mi) {
            int rA = wrow * 64 + mi * 16 + l15;
            int sl = q ^ ((rA >> 1) & 3);
            aF[mi] = *reinterpret_cast<const bf16x8*>(&As[p][0] + rA * BK_ + sl * 8);
        }
#pragma unroll
        for (int ni = 0; ni < 4; ++ni) {
            int rB = wcol * 64 + ni * 16 + l15;
            int sl = q ^ ((rB >> 1) & 3);
            bF[ni] = *reinterpret_cast<const bf16x8*>(&Bs[p][0] + rB * BK_ + sl * 8);
        }
        asm volatile("s_waitcnt lgkmcnt(0)" ::: "memory");
        __builtin_amdgcn_sched_barrier(0);   // rule 18: MFMA must not hoist
        __builtin_amdgcn_s_setprio(1);
#pragma unroll
        for (int mi = 0; mi < 4; ++mi)
#pragma unroll
            for (int ni = 0; ni < 4; ++ni)
                acc[mi][ni] = __builtin_amdgcn_mfma_f32_16x16x32_bf16(
                    aF[mi], bF[ni], acc[mi][ni], 0, 0, 0);
        __builtin_amdgcn_s_setprio(0);
    };

#define TILE(P, KS, DOSTAGE, VMN)                                         \
    do {                                                                  \
        asm volatile("s_waitcnt vmcnt(" #VMN ")" ::: "memory");           \
        __builtin_amdgcn_s_barrier();                                     \
        __builtin_amdgcn_sched_barrier(0);                                \
        compute_tile(P);                                                  \
        __builtin_amdgcn_s_barrier();                                     \
        __builtin_amdgcn_sched_barrier(0);                                \
        if (DOSTAGE) stage_tile(P, (KS) + 2);                             \
    } while (0)

    // prologue: two K-tiles in flight (8 gload_lds/thread outstanding)
    stage_tile(0, 0);
    stage_tile(1, 1);

    TILE(0, 0, 1, 4);
    TILE(1, 1, 1, 4);
    TILE(0, 2, 1, 4);
    TILE(1, 3, 1, 4);
    TILE(0, 4, 1, 4);
    TILE(1, 5, 1, 4);
    TILE(0, 6, 1, 4);
    TILE(1, 7, 1, 4);
    TILE(0, 8, 1, 4);
    TILE(1, 9, 1, 4);
    TILE(0, 10, 1, 4);
    TILE(1, 11, 1, 4);
    TILE(0, 12, 1, 4);
    TILE(1, 13, 1, 4);
    TILE(0, 14, 0, 4);
    TILE(1, 15, 0, 0);
#undef TILE

    // ---------------- epilogue ----------------
    int tC[4];
#pragma unroll
    for (int ni = 0; ni < 4; ++ni)
        tC[ni] = tg[col0 + wcol * 64 + ni * 16 + l15];

    float ps[4][4], ns[4][4];
    float cps[4], cns[4];
    int tR[4][4];
#pragma unroll
    for (int mi = 0; mi < 4; ++mi)
#pragma unroll
        for (int r = 0; r < 4; ++r) {
            ps[mi][r] = 0.f; ns[mi][r] = 0.f;
            tR[mi][r] = tg[row0 + wrow * 64 + mi * 16 + q * 4 + r];
        }
#pragma unroll
    for (int ni = 0; ni < 4; ++ni) { cps[ni] = 0.f; cns[ni] = 0.f; }

#pragma unroll
    for (int mi = 0; mi < 4; ++mi)
#pragma unroll
        for (int ni = 0; ni < 4; ++ni)
#pragma unroll
            for (int r = 0; r < 4; ++r) {
                float s = acc[mi][ni][r];
                bool same = (tR[mi][r] == tC[ni]);
                float e = __expf(same ? 1.0f - s : s);
                float pe = (same && (s < 1.0f)) ? e : 0.0f;
                float ne = same ? 0.0f : e;
                ps[mi][r] += pe; ns[mi][r] += ne;
                cps[ni]   += pe; cns[ni]   += ne;
            }

    // combine wave halves through LDS scratch = As[0] (4 KiB of 16 KiB;
    // last compute used buffer 1 -> disjoint; all As[0] reads sealed by the
    // tile-15 leading barrier which every wave has passed)
    float* scr = (float*)As;         // [0:256)=rowP, [256:512)=rowN,
                                     // [512:768)=colP, [768:1024)=colN
#pragma unroll
    for (int mi = 0; mi < 4; ++mi)
#pragma unroll
        for (int r = 0; r < 4; ++r) {
            float p = ps[mi][r];
            float n = ns[mi][r];
#pragma unroll
            for (int m = 1; m < 16; m <<= 1) {
                p += __shfl_xor(p, m, 64);
                n += __shfl_xor(n, m, 64);
            }
            if (l15 == 0) {
                int rloc = wrow * 64 + mi * 16 + q * 4 + r;
                scr[wcol * 128 + rloc]       = p;
                scr[256 + wcol * 128 + rloc] = n;
            }
        }

#pragma unroll
    for (int ni = 0; ni < 4; ++ni) {
        float p = cps[ni];
        float n = cns[ni];
        p += __shfl_xor(p, 16, 64); p += __shfl_xor(p, 32, 64);
        n += __shfl_xor(n, 16, 64); n += __shfl_xor(n, 32, 64);
        if (q == 0) {
            int cloc = wcol * 64 + ni * 16 + l15;
            scr[512 + wrow * 128 + cloc] = p;
            scr[768 + wrow * 128 + cloc] = n;
        }
    }
    __syncthreads();

    if (tid < 128) {
        int r = tid;
        size_t off = ((size_t)it * T_ + jt) * 128 + r;
        bufP[off] = scr[r]       + scr[128 + r];
        bufN[off] = scr[256 + r] + scr[384 + r];
    } else if (jt != it) {
        int c = tid - 128;
        size_t off = ((size_t)jt * T_ + it) * 128 + c;
        bufP[off] = scr[512 + c] + scr[640 + c];
        bufN[off] = scr[768 + c] + scr[896 + c];
    }
}

// ---------- kernel 3: reduce + finalize (64 blocks, atomic-chained) ----------
__global__ __launch_bounds__(256) void k_post(const float* __restrict__ bufP,
                                              const float* __restrict__ bufN,
                                              const int* __restrict__ tg,
                                              const int* __restrict__ hist32,
                                              const double* __restrict__ sim_last,
                                              double* __restrict__ gd,
                                              int* __restrict__ gi,
                                              float* __restrict__ out) {
    __shared__ int lh[NC_];
    __shared__ float sv[256];
    __shared__ double Rd[256], Pd[256], Nd[256];
    __shared__ int Ri[256], Pc[256], Nc[256];
    const int t   = blockIdx.x;       // 0..63
    const int tid = threadIdx.x;

    if (tid < NC_) {
        int a = 0;
#pragma unroll
        for (int b = 0; b < 32; ++b) a += hist32[b * NC_ + tid];
        lh[tid] = a;
    }

    const int half = tid >> 7;        // 0: psum, 1: nsum
    const int r    = tid & 127;
    const float* buf  = half ? bufN : bufP;
    const float* base = buf + (size_t)t * T_ * 128 + r;
    float s = 0.f;
#pragma unroll
    for (int o = 0; o < T_; ++o) s += base[o * 128];
    sv[tid] = s;
    __syncthreads();

    double rd = 0.0, pd = 0.0, nd = 0.0;
    int ri = 0, pc = 0, nc = 0;
    if (tid < 128) {
        int row = t * 128 + tid;
        bool ok = lh[tg[row]] < N_;
        rd = ok ? (double)(logf(sv[tid]) + logf(sv[128 + tid])) : 0.0;
        ri = ok ? 0 : 1;
        double sl = sim_last[row];
        int tlast = tg[N_ - 1];
        if (tg[row] == tlast) { if (sl < 1.0) { pd = sl; pc = 1; } }
        else                  { nd = sl; nc = 1; }
    }

    Rd[tid] = rd; Ri[tid] = ri;
    Pd[tid] = pd; Pc[tid] = pc;
    Nd[tid] = nd; Nc[tid] = nc;
    __syncthreads();
    for (int st = 128; st >= 1; st >>= 1) {
        if (tid < st) {
            Rd[tid] += Rd[tid + st]; Pd[tid] += Pd[tid + st]; Nd[tid] += Nd[tid + st];
            Ri[tid] += Ri[tid + st]; Pc[tid] += Pc[tid + st]; Nc[tid] += Nc[tid + st];
        }
        __syncthreads();
    }

    if (tid == 0) {
        atomicAdd(&gd[0], Rd[0]);
        atomicAdd(&gd[1], Pd[0]);
        atomicAdd(&gd[2], Nd[0]);
        atomicAdd(&gi[0], Ri[0]);
        atomicAdd(&gi[1], Pc[0]);
        atomicAdd(&gi[2], Nc[0]);
        __threadfence();
        int old = atomicAdd(&gi[3], 1);
        if (old == 63) {
            double A = atomicAdd(&gd[0], 0.0);
            double B = atomicAdd(&gd[1], 0.0);
            double C = atomicAdd(&gd[2], 0.0);
            int U = atomicAdd(&gi[0], 0);
            int V = atomicAdd(&gi[1], 0);
            int Y = atomicAdd(&gi[2], 0);
            out[0] = (float)(A / (double)N_);
            out[1] = (float)U / (float)N_;
            out[2] = (float)(B / (double)V);
            out[3] = (float)(C / (double)Y);
        }
    }
}

extern "C" void kernel_launch(void* const* d_in, const int* in_sizes, int n_in,
                              void* d_out, int out_size, void* d_ws, size_t ws_size,
                              hipStream_t stream) {
    const float* x  = (const float*)d_in[0];
    const int*   tg = (const int*)d_in[1];
    char* ws = (char*)d_ws;

    unsigned short* xb = (unsigned short*)ws;                 // 8 MB
    const size_t XB = (size_t)N_ * D_ * 2;                    // 8388608
    float*  bufP = (float*)(ws + XB);                         // 2 MB
    float*  bufN = (float*)(ws + XB + 2097152);               // 2 MB
    double* sim_last = (double*)(ws + XB + 4194304);          // 64 KB
    int*    hist32   = (int*)(ws + XB + 4194304 + 65536);     // 16 KB
    double* gd   = (double*)(ws + XB + 4194304 + 65536 + 16384);      // 3 doubles
    int*    gi   = (int*)(ws + XB + 4194304 + 65536 + 16384 + 64);    // 4 ints

    const int nblk_tri = T_ * (T_ + 1) / 2;                   // 2080

    hipLaunchKernelGGL(k_pre, dim3(4096 + 2048 + 32), dim3(256), 0, stream,
                       x, xb, tg, sim_last, hist32, gd, gi);
    hipLaunchKernelGGL(k_main, dim3(nblk_tri), dim3(256), 0, stream, xb, tg, bufP, bufN);
    hipLaunchKernelGGL(k_post, dim3(64), dim3(256), 0, stream,
                       bufP, bufN, tg, hist32, sim_last, gd, gi, (float*)d_out);
}